// Round 18
// baseline (83.097 us; speedup 1.0000x reference)
//
#include <hip/hip_runtime.h>
#include <hip/hip_bf16.h>
#include <cstdint>

#define NN 50000
#define NE 640000
#define DIM 128
#define CAP 64                            // bucket capacity; P(deg>64) ~ 1e-18
#define GEMM_BLOCKS 391                   // 2 tiles (128 rows) per block
#define FILL_BLOCKS (NE / 4 / 256)        // 625 (4 edges/thread, exact)
#define GATHER_BLOCKS (NN * 16 / 256)     // 3125 (exact)

typedef __attribute__((ext_vector_type(8))) short bf16x8;
typedef __attribute__((ext_vector_type(8))) unsigned short u16x8;
typedef __attribute__((ext_vector_type(4))) float f32x4;

union bfpack { bf16x8 v; uint32_t u[4]; };

// hardware packed f32x2 -> bf16x2 (RNE): v_cvt_pk_bf16_f32, 1 op per pair
static __device__ __forceinline__ uint32_t pk2bf(float lo, float hi) {
    __hip_bfloat162 t = __float22bfloat162_rn(make_float2(lo, hi));
    union { __hip_bfloat162 b; uint32_t u; } v;
    v.b = t;
    return v.u;
}
static __device__ __forceinline__ short f2bf(float f) {   // scalar path (epilogue)
    union { float f; uint32_t u; } v; v.f = f;
    uint32_t r = v.u + 0x7FFFu + ((v.u >> 16) & 1u);      // RNE
    return (short)(r >> 16);
}
static __device__ __forceinline__ float bf2f(unsigned short u) {
    union { uint32_t u; float f; } v; v.u = ((uint32_t)u) << 16;   // exact
    return v.f;
}

// ---------------------------------------------------------------- gemm (+ cnt zero)
// 391 blocks x 256 thr, TWO 64-row tiles per block (W-stage amortized over 128
// rows). Blocks 0..48 also zero the packed cnt array (200 KB) — safe: fill
// runs in a later dispatch. Bs[t], t=(n*4+kk)*64+lane holds 8 bf16 =
// W[k0..k0+8)[n*16+(lane&15)], k0=kk*32+(lane>>4)*8 — same slot->k bijection
// as the A-side x load, so the contraction is k-order-agnostic.
// h = x @ W stored bf16 (fp32 MFMA accum). Full-tile blocks (rbase+16<=NN,
// wave-uniform) take an unpredicated store path.
__global__ __launch_bounds__(256) void k_gemm(const float* __restrict__ x,
                                              const float* __restrict__ W,
                                              unsigned short* __restrict__ h_bf,
                                              int4* __restrict__ cnt4) {
    __shared__ bf16x8 Bs[2048];   // 32 KB
    const int tid = threadIdx.x;
    const int gid = blockIdx.x * 256 + tid;
    if (gid < NN / 4) cnt4[gid] = make_int4(0, 0, 0, 0);

    #pragma unroll
    for (int i = 0; i < 8; ++i) {
        const int t = tid + i * 256;
        const int n = t >> 8;
        const int kk = (t >> 6) & 3;
        const int l = t & 63;
        const int c = n * 16 + (l & 15);
        const int k0 = kk * 32 + (l >> 4) * 8;
        const float* wc = W + (size_t)k0 * DIM + c;
        bfpack t8;
        #pragma unroll
        for (int j = 0; j < 4; ++j)
            t8.u[j] = pk2bf(wc[(2 * j) * DIM], wc[(2 * j + 1) * DIM]);
        Bs[t] = t8.v;
    }
    __syncthreads();

    const int wave = tid >> 6;
    const int lane = tid & 63;
    const int kg = lane >> 4;                    // k-group 0..3
    const int col = lane & 15;

    #pragma unroll
    for (int tile = 0; tile < 2; ++tile) {
        const int rbase = (blockIdx.x * 2 + tile) * 64 + wave * 16;
        const int rA = rbase + (lane & 15);      // A-fragment row (m = lane&15)

        bf16x8 a[4];
        if (rA < NN) {
            const float* xr = x + (size_t)rA * DIM + kg * 8;
            #pragma unroll
            for (int kk = 0; kk < 4; ++kk) {
                const float4 f0 = *reinterpret_cast<const float4*>(xr + kk * 32);
                const float4 f1 = *reinterpret_cast<const float4*>(xr + kk * 32 + 4);
                bfpack t8;
                t8.u[0] = pk2bf(f0.x, f0.y);
                t8.u[1] = pk2bf(f0.z, f0.w);
                t8.u[2] = pk2bf(f1.x, f1.y);
                t8.u[3] = pk2bf(f1.z, f1.w);
                a[kk] = t8.v;
            }
        } else {
            #pragma unroll
            for (int kk = 0; kk < 4; ++kk) a[kk] = (bf16x8)0;
        }

        const int rC0 = rbase + (lane >> 4) * 4; // C rows: rC0 + i  (i=0..3)
        const bool full = (rbase + 16 <= NN);    // wave-uniform
        #pragma unroll
        for (int n = 0; n < 8; ++n) {
            f32x4 acc = {0.f, 0.f, 0.f, 0.f};
            #pragma unroll
            for (int kk = 0; kk < 4; ++kk) {
                const bf16x8 b = Bs[(n * 4 + kk) * 64 + lane];   // stride-1, conflict-free
                acc = __builtin_amdgcn_mfma_f32_16x16x32_bf16(a[kk], b, acc, 0, 0, 0);
            }
            if (full) {
                #pragma unroll
                for (int i = 0; i < 4; ++i)
                    h_bf[(size_t)(rC0 + i) * DIM + n * 16 + col] =
                        (unsigned short)f2bf(acc[i]);
            } else {
                #pragma unroll
                for (int i = 0; i < 4; ++i) {
                    const int r = rC0 + i;
                    if (r < NN)
                        h_bf[(size_t)r * DIM + n * 16 + col] =
                            (unsigned short)f2bf(acc[i]);
                }
            }
        }
    }
}

// ---------------------------------------------------------------- bucket fill
// R15 exact (best measured): fixed-capacity buckets, uint16 payload, packed
// counters, 4 edges/thread. Fill is write-transaction-bound (R14/R15 A/B);
// sharding was neutral (R16). After this kernel cnt[n] == deg(n).
__global__ __launch_bounds__(256) void k_fill(const int4* __restrict__ src4,
                                              const int4* __restrict__ dst4,
                                              int* __restrict__ cnt,
                                              unsigned short* __restrict__ srt) {
    const int i = blockIdx.x * 256 + threadIdx.x;   // < NE/4 exact
    const int4 s = src4[i];
    const int4 d = dst4[i];
    srt[((size_t)d.x << 6) + atomicAdd(&cnt[d.x], 1)] = (unsigned short)s.x;
    srt[((size_t)d.y << 6) + atomicAdd(&cnt[d.y], 1)] = (unsigned short)s.y;
    srt[((size_t)d.z << 6) + atomicAdd(&cnt[d.z], 1)] = (unsigned short)s.z;
    srt[((size_t)d.w << 6) + atomicAdd(&cnt[d.w], 1)] = (unsigned short)s.w;
}

// ---------------------------------------------------------------- gather + epilogue
// 16 lanes per dst node (ushort8 = 16B/lane covers 8 of 128 cols).
// deg/dinv inline from packed cnt (200 KB, L2-resident). acc = did*h[n] +
// sum ds*h[s]; out = relu(did*acc + b), written non-temporal (write-once).
// 8/4/1 MLP ladder: up to EIGHT independent 256B row gathers in flight —
// isolated A/B vs R17's 4-deep to test the latency-bound diagnosis.
__global__ __launch_bounds__(256) void k_gather(const int* __restrict__ cnt,
                                                const unsigned short* __restrict__ srt,
                                                const unsigned short* __restrict__ h_bf,
                                                const float* __restrict__ bias,
                                                float* __restrict__ out) {
    const int t = blockIdx.x * 256 + threadIdx.x;
    const int n = t >> 4;
    if (n >= NN) return;
    const int lane = t & 15;                     // columns lane*8 .. lane*8+7
    const u16x8* __restrict__ h8 = reinterpret_cast<const u16x8*>(h_bf);

    const int deg = cnt[n];
    const float did = rsqrtf((float)deg + 1.0f);

    float acc[8];
    {
        const u16x8 hv = h8[(size_t)n * 16 + lane];   // self loop: did*h[n]
        #pragma unroll
        for (int j = 0; j < 8; ++j) acc[j] = bf2f(hv[j]) * did;
    }

    const unsigned short* __restrict__ bucket = srt + ((size_t)n << 6);
    int p = 0;
    for (; p + 7 < deg; p += 8) {
        int s[8];
        #pragma unroll
        for (int q = 0; q < 8; ++q) s[q] = bucket[p + q];
        u16x8 v[8];
        #pragma unroll
        for (int q = 0; q < 8; ++q) v[q] = h8[(size_t)s[q] * 16 + lane];
        float nw[8];
        #pragma unroll
        for (int q = 0; q < 8; ++q) nw[q] = rsqrtf((float)cnt[s[q]] + 1.0f);
        #pragma unroll
        for (int q = 0; q < 8; ++q)
            #pragma unroll
            for (int j = 0; j < 8; ++j) acc[j] = fmaf(bf2f(v[q][j]), nw[q], acc[j]);
    }
    for (; p + 3 < deg; p += 4) {
        int s[4];
        #pragma unroll
        for (int q = 0; q < 4; ++q) s[q] = bucket[p + q];
        u16x8 v[4];
        #pragma unroll
        for (int q = 0; q < 4; ++q) v[q] = h8[(size_t)s[q] * 16 + lane];
        float nw[4];
        #pragma unroll
        for (int q = 0; q < 4; ++q) nw[q] = rsqrtf((float)cnt[s[q]] + 1.0f);
        #pragma unroll
        for (int q = 0; q < 4; ++q)
            #pragma unroll
            for (int j = 0; j < 8; ++j) acc[j] = fmaf(bf2f(v[q][j]), nw[q], acc[j]);
    }
    for (; p < deg; ++p) {
        const int s0 = bucket[p];
        const float n0 = rsqrtf((float)cnt[s0] + 1.0f);
        const u16x8 v0 = h8[(size_t)s0 * 16 + lane];
        #pragma unroll
        for (int j = 0; j < 8; ++j) acc[j] = fmaf(bf2f(v0[j]), n0, acc[j]);
    }

    const float4 bv0 = reinterpret_cast<const float4*>(bias)[lane * 2];
    const float4 bv1 = reinterpret_cast<const float4*>(bias)[lane * 2 + 1];
    f32x4 o0, o1;
    o0[0] = fmaxf(fmaf(did, acc[0], bv0.x), 0.f);
    o0[1] = fmaxf(fmaf(did, acc[1], bv0.y), 0.f);
    o0[2] = fmaxf(fmaf(did, acc[2], bv0.z), 0.f);
    o0[3] = fmaxf(fmaf(did, acc[3], bv0.w), 0.f);
    o1[0] = fmaxf(fmaf(did, acc[4], bv1.x), 0.f);
    o1[1] = fmaxf(fmaf(did, acc[5], bv1.y), 0.f);
    o1[2] = fmaxf(fmaf(did, acc[6], bv1.z), 0.f);
    o1[3] = fmaxf(fmaf(did, acc[7], bv1.w), 0.f);
    f32x4* orow = reinterpret_cast<f32x4*>(out + (size_t)n * DIM) + lane * 2;
    __builtin_nontemporal_store(o0, orow);
    __builtin_nontemporal_store(o1, orow + 1);
}

// ----------------------------------------------------------------
extern "C" void kernel_launch(void* const* d_in, const int* in_sizes, int n_in,
                              void* d_out, int out_size, void* d_ws, size_t ws_size,
                              hipStream_t stream) {
    const float* x  = (const float*)d_in[0];
    const int*   ei = (const int*)d_in[1];   // [2, NE]: src row then dst row
    const float* W  = (const float*)d_in[2];
    const float* b  = (const float*)d_in[3];
    float* out = (float*)d_out;

    const int* src = ei;
    const int* dst = ei + NE;

    // workspace (~19.4 MB), 16B-aligned segments:
    // h_bf [NN*DIM u16] | cnt [NN i32, packed] | srt [NN*CAP u16]
    unsigned short* h_bf = (unsigned short*)d_ws;
    int* cnt = (int*)(h_bf + (size_t)NN * DIM);
    unsigned short* srt = (unsigned short*)(cnt + NN);

    k_gemm<<<GEMM_BLOCKS, 256, 0, stream>>>(x, W, h_bf, (int4*)cnt);
    k_fill<<<FILL_BLOCKS, 256, 0, stream>>>((const int4*)src, (const int4*)dst,
                                            cnt, srt);
    k_gather<<<GATHER_BLOCKS, 256, 0, stream>>>(cnt, srt, h_bf, b, out);
}

// Round 19
// 77.826 us; speedup vs baseline: 1.0677x; 1.0677x over previous
//
#include <hip/hip_runtime.h>
#include <hip/hip_bf16.h>
#include <cstdint>

#define NN 50000
#define NE 640000
#define DIM 128
#define CAP 64                            // bucket capacity; P(deg>64) ~ 1e-18
#define GEMM_BLOCKS 391                   // 2 tiles (128 rows) per block
#define FILL_BLOCKS (NE / 4 / 256)        // 625 (4 edges/thread, exact)
#define GATHER_BLOCKS (NN * 16 / 256)     // 3125 (exact)

typedef __attribute__((ext_vector_type(8))) short bf16x8;
typedef __attribute__((ext_vector_type(8))) unsigned short u16x8;
typedef __attribute__((ext_vector_type(4))) float f32x4;

union bfpack { bf16x8 v; uint32_t u[4]; };

// hardware packed f32x2 -> bf16x2 (RNE): v_cvt_pk_bf16_f32, 1 op per pair
static __device__ __forceinline__ uint32_t pk2bf(float lo, float hi) {
    __hip_bfloat162 t = __float22bfloat162_rn(make_float2(lo, hi));
    union { __hip_bfloat162 b; uint32_t u; } v;
    v.b = t;
    return v.u;
}
static __device__ __forceinline__ short f2bf(float f) {   // scalar path (epilogue)
    union { float f; uint32_t u; } v; v.f = f;
    uint32_t r = v.u + 0x7FFFu + ((v.u >> 16) & 1u);      // RNE
    return (short)(r >> 16);
}
static __device__ __forceinline__ float bf2f(unsigned short u) {
    union { uint32_t u; float f; } v; v.u = ((uint32_t)u) << 16;   // exact
    return v.f;
}

// ---------------------------------------------------------------- gemm (+ cnt zero)
// 391 blocks x 256 thr, TWO 64-row tiles per block (W-stage amortized over 128
// rows). Blocks 0..48 also zero the packed cnt array (200 KB) — safe: fill
// runs in a later dispatch. Bs[t], t=(n*4+kk)*64+lane holds 8 bf16 =
// W[k0..k0+8)[n*16+(lane&15)], k0=kk*32+(lane>>4)*8 — same slot->k bijection
// as the A-side x load, so the contraction is k-order-agnostic.
// h = x @ W stored bf16 (fp32 MFMA accum). Full-tile blocks (rbase+16<=NN,
// wave-uniform) take an unpredicated store path.
__global__ __launch_bounds__(256) void k_gemm(const float* __restrict__ x,
                                              const float* __restrict__ W,
                                              unsigned short* __restrict__ h_bf,
                                              int4* __restrict__ cnt4) {
    __shared__ bf16x8 Bs[2048];   // 32 KB
    const int tid = threadIdx.x;
    const int gid = blockIdx.x * 256 + tid;
    if (gid < NN / 4) cnt4[gid] = make_int4(0, 0, 0, 0);

    #pragma unroll
    for (int i = 0; i < 8; ++i) {
        const int t = tid + i * 256;
        const int n = t >> 8;
        const int kk = (t >> 6) & 3;
        const int l = t & 63;
        const int c = n * 16 + (l & 15);
        const int k0 = kk * 32 + (l >> 4) * 8;
        const float* wc = W + (size_t)k0 * DIM + c;
        bfpack t8;
        #pragma unroll
        for (int j = 0; j < 4; ++j)
            t8.u[j] = pk2bf(wc[(2 * j) * DIM], wc[(2 * j + 1) * DIM]);
        Bs[t] = t8.v;
    }
    __syncthreads();

    const int wave = tid >> 6;
    const int lane = tid & 63;
    const int kg = lane >> 4;                    // k-group 0..3
    const int col = lane & 15;

    #pragma unroll
    for (int tile = 0; tile < 2; ++tile) {
        const int rbase = (blockIdx.x * 2 + tile) * 64 + wave * 16;
        const int rA = rbase + (lane & 15);      // A-fragment row (m = lane&15)

        bf16x8 a[4];
        if (rA < NN) {
            const float* xr = x + (size_t)rA * DIM + kg * 8;
            #pragma unroll
            for (int kk = 0; kk < 4; ++kk) {
                const float4 f0 = *reinterpret_cast<const float4*>(xr + kk * 32);
                const float4 f1 = *reinterpret_cast<const float4*>(xr + kk * 32 + 4);
                bfpack t8;
                t8.u[0] = pk2bf(f0.x, f0.y);
                t8.u[1] = pk2bf(f0.z, f0.w);
                t8.u[2] = pk2bf(f1.x, f1.y);
                t8.u[3] = pk2bf(f1.z, f1.w);
                a[kk] = t8.v;
            }
        } else {
            #pragma unroll
            for (int kk = 0; kk < 4; ++kk) a[kk] = (bf16x8)0;
        }

        const int rC0 = rbase + (lane >> 4) * 4; // C rows: rC0 + i  (i=0..3)
        const bool full = (rbase + 16 <= NN);    // wave-uniform
        #pragma unroll
        for (int n = 0; n < 8; ++n) {
            f32x4 acc = {0.f, 0.f, 0.f, 0.f};
            #pragma unroll
            for (int kk = 0; kk < 4; ++kk) {
                const bf16x8 b = Bs[(n * 4 + kk) * 64 + lane];   // stride-1, conflict-free
                acc = __builtin_amdgcn_mfma_f32_16x16x32_bf16(a[kk], b, acc, 0, 0, 0);
            }
            if (full) {
                #pragma unroll
                for (int i = 0; i < 4; ++i)
                    h_bf[(size_t)(rC0 + i) * DIM + n * 16 + col] =
                        (unsigned short)f2bf(acc[i]);
            } else {
                #pragma unroll
                for (int i = 0; i < 4; ++i) {
                    const int r = rC0 + i;
                    if (r < NN)
                        h_bf[(size_t)r * DIM + n * 16 + col] =
                            (unsigned short)f2bf(acc[i]);
                }
            }
        }
    }
}

// ---------------------------------------------------------------- bucket fill
// R15 exact (best measured): fixed-capacity buckets, uint16 payload, packed
// counters, 4 edges/thread. Fill is write-transaction-bound (R14/R15 A/B);
// sharding was neutral (R16). After this kernel cnt[n] == deg(n).
__global__ __launch_bounds__(256) void k_fill(const int4* __restrict__ src4,
                                              const int4* __restrict__ dst4,
                                              int* __restrict__ cnt,
                                              unsigned short* __restrict__ srt) {
    const int i = blockIdx.x * 256 + threadIdx.x;   // < NE/4 exact
    const int4 s = src4[i];
    const int4 d = dst4[i];
    srt[((size_t)d.x << 6) + atomicAdd(&cnt[d.x], 1)] = (unsigned short)s.x;
    srt[((size_t)d.y << 6) + atomicAdd(&cnt[d.y], 1)] = (unsigned short)s.y;
    srt[((size_t)d.z << 6) + atomicAdd(&cnt[d.z], 1)] = (unsigned short)s.z;
    srt[((size_t)d.w << 6) + atomicAdd(&cnt[d.w], 1)] = (unsigned short)s.w;
}

// ---------------------------------------------------------------- gather + epilogue
// 16 lanes per dst node (ushort8 = 16B/lane covers 8 of 128 cols).
// deg/dinv inline from packed cnt (200 KB, L2-resident). acc = did*h[n] +
// sum ds*h[s]; out = relu(did*acc + b), written non-temporal (write-once).
// 4-deep unroll (measured optimum: 8-deep regressed in R14 and R18): four
// independent 256B row gathers in flight; fp32 accumulate.
__global__ __launch_bounds__(256) void k_gather(const int* __restrict__ cnt,
                                                const unsigned short* __restrict__ srt,
                                                const unsigned short* __restrict__ h_bf,
                                                const float* __restrict__ bias,
                                                float* __restrict__ out) {
    const int t = blockIdx.x * 256 + threadIdx.x;
    const int n = t >> 4;
    if (n >= NN) return;
    const int lane = t & 15;                     // columns lane*8 .. lane*8+7
    const u16x8* __restrict__ h8 = reinterpret_cast<const u16x8*>(h_bf);

    const int deg = cnt[n];
    const float did = rsqrtf((float)deg + 1.0f);

    float acc[8];
    {
        const u16x8 hv = h8[(size_t)n * 16 + lane];   // self loop: did*h[n]
        #pragma unroll
        for (int j = 0; j < 8; ++j) acc[j] = bf2f(hv[j]) * did;
    }

    const unsigned short* __restrict__ bucket = srt + ((size_t)n << 6);
    int p = 0;
    for (; p + 3 < deg; p += 4) {
        const int s0 = bucket[p],     s1 = bucket[p + 1];
        const int s2 = bucket[p + 2], s3 = bucket[p + 3];
        const float n0 = rsqrtf((float)cnt[s0] + 1.0f);
        const float n1 = rsqrtf((float)cnt[s1] + 1.0f);
        const float n2 = rsqrtf((float)cnt[s2] + 1.0f);
        const float n3 = rsqrtf((float)cnt[s3] + 1.0f);
        const u16x8 v0 = h8[(size_t)s0 * 16 + lane];
        const u16x8 v1 = h8[(size_t)s1 * 16 + lane];
        const u16x8 v2 = h8[(size_t)s2 * 16 + lane];
        const u16x8 v3 = h8[(size_t)s3 * 16 + lane];
        #pragma unroll
        for (int j = 0; j < 8; ++j) acc[j] = fmaf(bf2f(v0[j]), n0, acc[j]);
        #pragma unroll
        for (int j = 0; j < 8; ++j) acc[j] = fmaf(bf2f(v1[j]), n1, acc[j]);
        #pragma unroll
        for (int j = 0; j < 8; ++j) acc[j] = fmaf(bf2f(v2[j]), n2, acc[j]);
        #pragma unroll
        for (int j = 0; j < 8; ++j) acc[j] = fmaf(bf2f(v3[j]), n3, acc[j]);
    }
    for (; p < deg; ++p) {
        const int s0 = bucket[p];
        const float n0 = rsqrtf((float)cnt[s0] + 1.0f);
        const u16x8 v0 = h8[(size_t)s0 * 16 + lane];
        #pragma unroll
        for (int j = 0; j < 8; ++j) acc[j] = fmaf(bf2f(v0[j]), n0, acc[j]);
    }

    const float4 bv0 = reinterpret_cast<const float4*>(bias)[lane * 2];
    const float4 bv1 = reinterpret_cast<const float4*>(bias)[lane * 2 + 1];
    f32x4 o0, o1;
    o0[0] = fmaxf(fmaf(did, acc[0], bv0.x), 0.f);
    o0[1] = fmaxf(fmaf(did, acc[1], bv0.y), 0.f);
    o0[2] = fmaxf(fmaf(did, acc[2], bv0.z), 0.f);
    o0[3] = fmaxf(fmaf(did, acc[3], bv0.w), 0.f);
    o1[0] = fmaxf(fmaf(did, acc[4], bv1.x), 0.f);
    o1[1] = fmaxf(fmaf(did, acc[5], bv1.y), 0.f);
    o1[2] = fmaxf(fmaf(did, acc[6], bv1.z), 0.f);
    o1[3] = fmaxf(fmaf(did, acc[7], bv1.w), 0.f);
    f32x4* orow = reinterpret_cast<f32x4*>(out + (size_t)n * DIM) + lane * 2;
    __builtin_nontemporal_store(o0, orow);
    __builtin_nontemporal_store(o1, orow + 1);
}

// ----------------------------------------------------------------
extern "C" void kernel_launch(void* const* d_in, const int* in_sizes, int n_in,
                              void* d_out, int out_size, void* d_ws, size_t ws_size,
                              hipStream_t stream) {
    const float* x  = (const float*)d_in[0];
    const int*   ei = (const int*)d_in[1];   // [2, NE]: src row then dst row
    const float* W  = (const float*)d_in[2];
    const float* b  = (const float*)d_in[3];
    float* out = (float*)d_out;

    const int* src = ei;
    const int* dst = ei + NE;

    // workspace (~19.4 MB), 16B-aligned segments:
    // h_bf [NN*DIM u16] | cnt [NN i32, packed] | srt [NN*CAP u16]
    unsigned short* h_bf = (unsigned short*)d_ws;
    int* cnt = (int*)(h_bf + (size_t)NN * DIM);
    unsigned short* srt = (unsigned short*)(cnt + NN);

    k_gemm<<<GEMM_BLOCKS, 256, 0, stream>>>(x, W, h_bf, (int4*)cnt);
    k_fill<<<FILL_BLOCKS, 256, 0, stream>>>((const int4*)src, (const int4*)dst,
                                            cnt, srt);
    k_gather<<<GATHER_BLOCKS, 256, 0, stream>>>(cnt, srt, h_bf, b, out);
}